// Round 12
// baseline (140.447 us; speedup 1.0000x reference)
//
#include <hip/hip_runtime.h>

#define NV 13824   // 24*24*24 voxels per batch
#define CCH 64     // channels
#define NB 2       // batch

// ---------------------------------------------------------------------------
// Kernel 1 (v7, unchanged): q/k/v projections in the C^T orientation.
// PROBE NOTE (round 12): launched 3x (idempotent) so dur_us = base + 2*t_qkv,
// separating t_qkv from the fixed harness overhead F (F + t_qkv = 88 was
// unidentifiable from rounds 6-11).
// ---------------------------------------------------------------------------
__global__ __launch_bounds__(256) void qkv_kernel(
    const float* __restrict__ x,
    const float* __restrict__ Wq, const float* __restrict__ bq,
    const float* __restrict__ Wk, const float* __restrict__ bk,
    const float* __restrict__ Wv, const float* __restrict__ bv,
    float* __restrict__ qo, float* __restrict__ ko, float* __restrict__ vo)
{
    __shared__ float  sW[32 * 64];     // 8KB   [ol][c], pre-scaled
    __shared__ float  sB2[32];
    __shared__ float4 sO[32 * 65];     // 33.3KB [ol][n-f4], row pad 1 f4

    const int t   = threadIdx.x;
    const int bid = blockIdx.x;
    const int lb  = (bid & 7) * 81 + (bid >> 3);   // bijective XCD chunking
    const int oc  = lb % 6;            // output chunk 0..5
    const int nch = lb / 6;            // n-chunk 0..107 (256 voxels each)
    const int m   = oc >> 1;           // tensor 0=q 1=k 2=v
    const int ch0 = (oc & 1) * 32;     // channel base within tensor
    const int b   = nch / 54;
    const int nn  = (nch - b * 54) * 256;   // 256 | NV: no batch straddle
    const float sc = (m == 0) ? 0.25f : 1.0f;

    {
        const float* const Ws[3] = {Wq, Wk, Wv};
        const float* const bs[3] = {bq, bk, bv};
        const float4* src = (const float4*)(Ws[m] + ch0 * 64);
        float4* dst = (float4*)sW;
        #pragma unroll
        for (int g = 0; g < 2; ++g) {
            float4 wv4 = src[g * 256 + t];
            wv4.x *= sc; wv4.y *= sc; wv4.z *= sc; wv4.w *= sc;
            dst[g * 256 + t] = wv4;
        }
        if (t < 32) sB2[t] = bs[m][ch0 + t] * sc;
    }
    __syncthreads();

    const int tn = t & 63;             // n-lane: 4 voxels at tn*4
    const int tw = t >> 6;             // wave id: outputs tw*8 .. tw*8+7
    const float* xp = x + (size_t)b * CCH * NV + nn + tn * 4;
    const float4* sW4 = (const float4*)sW;   // [ol][16 c-f4]

    float4 acc[8];
    #pragma unroll
    for (int i = 0; i < 8; ++i) acc[i] = make_float4(0.f, 0.f, 0.f, 0.f);

    #pragma unroll 4
    for (int c4 = 0; c4 < 16; ++c4) {
        float4 w4[8];
        #pragma unroll
        for (int i = 0; i < 8; ++i) w4[i] = sW4[(tw * 8 + i) * 16 + c4];
        #pragma unroll
        for (int cc = 0; cc < 4; ++cc) {
            const float4 xv = *(const float4*)(xp + (size_t)(c4 * 4 + cc) * NV);
            #pragma unroll
            for (int i = 0; i < 8; ++i) {
                const float ws = (cc == 0) ? w4[i].x : (cc == 1) ? w4[i].y
                               : (cc == 2) ? w4[i].z : w4[i].w;
                acc[i].x += xv.x * ws; acc[i].y += xv.y * ws;
                acc[i].z += xv.z * ws; acc[i].w += xv.w * ws;
            }
        }
    }

    #pragma unroll
    for (int i = 0; i < 8; ++i) {
        const int ol = tw * 8 + i;
        const float bb = sB2[ol];
        float4 a = acc[i];
        a.x += bb; a.y += bb; a.z += bb; a.w += bb;
        sO[ol * 65 + tn] = a;
    }
    __syncthreads();

    float* const outs[3] = {qo, ko, vo};
    const float* sOf = (const float*)sO;     // [ol][260 floats]
    float* ob = outs[m] + (size_t)(b * NV + nn) * 64 + ch0;
    #pragma unroll
    for (int it = 0; it < 8; ++it) {
        const int g   = it * 256 + t;
        const int n   = g >> 3;          // 0..255
        const int of4 = g & 7;           // which 4-channel group
        float4 o4;
        o4.x = sOf[(of4 * 4 + 0) * 260 + n];
        o4.y = sOf[(of4 * 4 + 1) * 260 + n];
        o4.z = sOf[(of4 * 4 + 2) * 260 + n];
        o4.w = sOf[(of4 * 4 + 3) * 260 + n];
        *(float4*)(ob + (size_t)n * 64 + of4 * 4) = o4;
    }
}

// ---------------------------------------------------------------------------
// Kernel 2 (v4, unchanged): local attention.
// ---------------------------------------------------------------------------
__global__ __launch_bounds__(256) void attn_kernel(
    const float* __restrict__ x,
    const float* __restrict__ qw,
    const float* __restrict__ kw,
    const float* __restrict__ vw,
    float* __restrict__ out)
{
    __shared__ float so[32][65];   // padded: conflict-free

    const int t    = threadIdx.x;
    const int bid  = blockIdx.x;
    const int lb   = (bid & 7) * 108 + (bid >> 3);   // bijective XCD chunking
    const int half = t & 1;
    const int head = (t >> 1) & 3;
    const int vb   = t >> 3;             // 0..31
    const int n0g  = lb * 32;            // 32 | NV -> no batch straddle
    const int gr   = n0g + vb;
    const int b    = gr / NV;
    const int n    = gr - b * NV;
    const int d    = n / 576;
    const int rem  = n - d * 576;
    const int r    = rem / 24;
    const int w    = rem - r * 24;
    const int coff = head * 16 + half * 8;

    int   idx[27];
    float msk[27];
    #pragma unroll
    for (int i3 = 0; i3 < 3; ++i3)
    #pragma unroll
    for (int j3 = 0; j3 < 3; ++j3)
    #pragma unroll
    for (int l3 = 0; l3 < 3; ++l3) {
        const int dd = d + i3 - 1;
        const int rr = r + j3 - 1;
        const int ww = w + l3 - 1;
        const bool ok = ((unsigned)dd < 24u) & ((unsigned)rr < 24u) & ((unsigned)ww < 24u);
        const int jj = (i3 * 3 + j3) * 3 + l3;
        idx[jj] = ok ? ((dd * 24 + rr) * 24 + ww) : n;
        msk[jj] = ok ? 1.f : 0.f;
    }

    const float4* qp = (const float4*)(qw + (size_t)gr * 64 + coff);
    const float4 q0 = qp[0], q1 = qp[1];

    const float* kbase = kw + (size_t)b * NV * 64 + coff;

    float logit[27];
    #pragma unroll
    for (int j = 0; j < 27; ++j) {
        const float4* kp = (const float4*)(kbase + (size_t)idx[j] * 64);
        const float4 k0 = kp[0], k1 = kp[1];
        float a;
        a  = q0.x * k0.x + q0.y * k0.y + q0.z * k0.z + q0.w * k0.w;
        a += q1.x * k1.x + q1.y * k1.y + q1.z * k1.z + q1.w * k1.w;
        logit[j] = a * msk[j];
    }
    #pragma unroll
    for (int j = 0; j < 27; ++j)
        logit[j] += __shfl_xor(logit[j], 1, 64);   // combine 8+8 dim halves

    float ssum = 0.f;
    #pragma unroll
    for (int j = 0; j < 27; ++j) {
        const float e = __expf(logit[j]);   // OOB: exp(0)=1 participates
        logit[j] = e;
        ssum += e;
    }
    const float inv = 1.f / ssum;

    float a0=0.f,a1=0.f,a2=0.f,a3=0.f,a4=0.f,a5=0.f,a6=0.f,a7=0.f;
    const float* vbase = vw + (size_t)b * NV * 64 + coff;
    #pragma unroll
    for (int j = 0; j < 27; ++j) {
        const float p = logit[j] * msk[j];   // OOB contributes v = 0
        const float4* vp = (const float4*)(vbase + (size_t)idx[j] * 64);
        const float4 v0 = vp[0], v1 = vp[1];
        a0 += p * v0.x; a1 += p * v0.y; a2 += p * v0.z; a3 += p * v0.w;
        a4 += p * v1.x; a5 += p * v1.y; a6 += p * v1.z; a7 += p * v1.w;
    }

    so[vb][coff + 0] = a0 * inv;  so[vb][coff + 1] = a1 * inv;
    so[vb][coff + 2] = a2 * inv;  so[vb][coff + 3] = a3 * inv;
    so[vb][coff + 4] = a4 * inv;  so[vb][coff + 5] = a5 * inv;
    so[vb][coff + 6] = a6 * inv;  so[vb][coff + 7] = a7 * inv;
    __syncthreads();

    const int vv = t & 31;
    const int cg = t >> 5;
    const int bs = n0g / NV;
    const int nb0 = n0g - bs * NV;
    const float* xb = x   + (size_t)bs * CCH * NV + nb0 + vv;
    float*       ob = out + (size_t)bs * CCH * NV + nb0 + vv;
    #pragma unroll
    for (int i = 0; i < 8; ++i) {
        const int c = cg * 8 + i;
        ob[(size_t)c * NV] = xb[(size_t)c * NV] + so[vv][c];
    }
}

// ---------------------------------------------------------------------------
extern "C" void kernel_launch(void* const* d_in, const int* in_sizes, int n_in,
                              void* d_out, int out_size, void* d_ws, size_t ws_size,
                              hipStream_t stream) {
    const float* x  = (const float*)d_in[0];
    // d_in[1] = cemb, unused by the reference forward
    const float* Wq = (const float*)d_in[2];
    const float* bq = (const float*)d_in[3];
    const float* Wk = (const float*)d_in[4];
    const float* bk = (const float*)d_in[5];
    const float* Wv = (const float*)d_in[6];
    const float* bv = (const float*)d_in[7];
    float* out = (float*)d_out;

    float* ws = (float*)d_ws;
    const size_t RC = (size_t)NB * NV * CCH;   // 1,769,472 floats per tensor
    float* q = ws;
    float* k = ws + RC;
    float* v = ws + 2 * RC;

    // PROBE: qkv launched 3x (idempotent). dur_us = F + attn + 3*t_qkv,
    // vs round-11 baseline F + attn + t_qkv = 107.9 -> t_qkv = (dur-107.9)/2.
    qkv_kernel<<<648, 256, 0, stream>>>(x, Wq, bq, Wk, bk, Wv, bv, q, k, v);
    qkv_kernel<<<648, 256, 0, stream>>>(x, Wq, bq, Wk, bk, Wv, bv, q, k, v);
    qkv_kernel<<<648, 256, 0, stream>>>(x, Wq, bq, Wk, bk, Wv, bv, q, k, v);
    attn_kernel<<<864, 256, 0, stream>>>(x, q, k, v, out);
}

// Round 13
// 109.067 us; speedup vs baseline: 1.2877x; 1.2877x over previous
//
#include <hip/hip_runtime.h>

#define NV 13824   // 24*24*24 voxels per batch
#define CCH 64     // channels
#define NB 2       // batch

// ---------------------------------------------------------------------------
// Kernel 1 (v8): C^T-orientation qkv GEMM, occupancy-doubled vs v7.
// Block = (32-output chunk oc) x (128 voxels). 1296 blocks (~5 waves/SIMD).
// Thread = 4 outputs x 4 voxels (acc = 4 x float4-over-n).
// Dense 512B x-streams per wave; W (8KB) broadcast from LDS; q-scale+bias
// prefolded; epilogue via padded LDS transpose sO[32][33]f4 (17KB) ->
// full-sector 128B-per-voxel-chunk stores. XCD chunking: 1296 = 8*162.
// ---------------------------------------------------------------------------
__global__ __launch_bounds__(256) void qkv_kernel(
    const float* __restrict__ x,
    const float* __restrict__ Wq, const float* __restrict__ bq,
    const float* __restrict__ Wk, const float* __restrict__ bk,
    const float* __restrict__ Wv, const float* __restrict__ bv,
    float* __restrict__ qo, float* __restrict__ ko, float* __restrict__ vo)
{
    __shared__ float  sW[32 * 64];     // 8KB [ol][c], pre-scaled
    __shared__ float  sB2[32];
    __shared__ float4 sO[32 * 33];     // 16.9KB [ol][n-f4], +1 f4 row pad

    const int t   = threadIdx.x;
    const int bid = blockIdx.x;
    const int lb  = (bid & 7) * 162 + (bid >> 3);   // bijective XCD chunking
    const int oc  = lb % 6;            // output chunk 0..5
    const int nch = lb / 6;            // n-chunk 0..215 (128 voxels each)
    const int m   = oc >> 1;           // tensor 0=q 1=k 2=v
    const int ch0 = (oc & 1) * 32;     // channel base within tensor
    const int b   = nch / 108;
    const int nn  = (nch - b * 108) * 128;   // 128 | NV: no batch straddle
    const float sc = (m == 0) ? 0.25f : 1.0f;

    // stage W chunk (32 rows x 64) pre-scaled; dense contiguous reads
    {
        const float* const Ws[3] = {Wq, Wk, Wv};
        const float* const bs[3] = {bq, bk, bv};
        const float4* src = (const float4*)(Ws[m] + ch0 * 64);
        float4* dst = (float4*)sW;
        #pragma unroll
        for (int g = 0; g < 2; ++g) {
            float4 wv4 = src[g * 256 + t];
            wv4.x *= sc; wv4.y *= sc; wv4.z *= sc; wv4.w *= sc;
            dst[g * 256 + t] = wv4;
        }
        if (t < 32) sB2[t] = bs[m][ch0 + t] * sc;
    }
    __syncthreads();

    const int tn = t & 31;             // n-f4 lane: voxels tn*4..tn*4+3
    const int tw = t >> 5;             // 0..7: outputs tw*4..tw*4+3
    const float* xp = x + (size_t)b * CCH * NV + nn + tn * 4;
    const float4* sW4 = (const float4*)sW;   // [ol][16 c-f4]

    float4 acc[4];
    #pragma unroll
    for (int i = 0; i < 4; ++i) acc[i] = make_float4(0.f, 0.f, 0.f, 0.f);

    #pragma unroll 4
    for (int c4 = 0; c4 < 16; ++c4) {
        float4 w4[4];
        #pragma unroll
        for (int i = 0; i < 4; ++i) w4[i] = sW4[(tw * 4 + i) * 16 + c4];
        #pragma unroll
        for (int cc = 0; cc < 4; ++cc) {
            const float4 xv = *(const float4*)(xp + (size_t)(c4 * 4 + cc) * NV);
            #pragma unroll
            for (int i = 0; i < 4; ++i) {
                const float ws = (cc == 0) ? w4[i].x : (cc == 1) ? w4[i].y
                               : (cc == 2) ? w4[i].z : w4[i].w;
                acc[i].x += xv.x * ws; acc[i].y += xv.y * ws;
                acc[i].z += xv.z * ws; acc[i].w += xv.w * ws;
            }
        }
    }

    // deposit (+bias) into LDS transpose: b128, conflict-free
    #pragma unroll
    for (int i = 0; i < 4; ++i) {
        const int ol = tw * 4 + i;
        const float bb = sB2[ol];
        float4 a = acc[i];
        a.x += bb; a.y += bb; a.z += bb; a.w += bb;
        sO[ol * 33 + tn] = a;
    }
    __syncthreads();

    // store [n][ch0..ch0+32) pieces: 128B per voxel, full 32B sectors
    float* const outs[3] = {qo, ko, vo};
    const float* sOf = (const float*)sO;     // [ol][132 floats]
    float* ob = outs[m] + (size_t)(b * NV + nn) * 64 + ch0;
    #pragma unroll
    for (int it = 0; it < 4; ++it) {
        const int g   = it * 256 + t;
        const int n   = g >> 3;          // voxel 0..127
        const int of4 = g & 7;           // 4-channel group
        float4 o4;
        o4.x = sOf[(of4 * 4 + 0) * 132 + n];
        o4.y = sOf[(of4 * 4 + 1) * 132 + n];
        o4.z = sOf[(of4 * 4 + 2) * 132 + n];
        o4.w = sOf[(of4 * 4 + 3) * 132 + n];
        *(float4*)(ob + (size_t)n * 64 + of4 * 4) = o4;
    }
}

// ---------------------------------------------------------------------------
// Kernel 2 (v6): local attention, 16 lanes per voxel (4 ch each).
// 1728 blocks x 4 waves = 6.75 waves/SIMD (v4 was 3.4). Register diet:
// per-tap offsets are compile-time (nj = n64 + (ok ? OFF*64 : 0)), validity
// packed into 27-bit mb -> no idx/msk arrays (~50 VGPR). Taps branch-free,
// unconditional loads; OOB logit = 0 enters softmax, v masked to 0
// (exact zero-padded-k reference semantics). Logits combined via
// shfl_xor(1) + shfl_xor(2) across the head's 4 lanes.
// Output via padded LDS transpose sO4[16][17]f4 (4.4KB); residual/store in
// 64B-dense segments. XCD chunking: 1728 = 8*216.
// ---------------------------------------------------------------------------
__global__ __launch_bounds__(256) void attn_kernel(
    const float* __restrict__ x,
    const float* __restrict__ qw,
    const float* __restrict__ kw,
    const float* __restrict__ vw,
    float* __restrict__ out)
{
    __shared__ float4 sO4[16 * 17];   // [vox][c4 + pad]

    const int t   = threadIdx.x;
    const int bid = blockIdx.x;
    const int lb  = (bid & 7) * 216 + (bid >> 3);   // bijective XCD chunking
    const int c4i = t & 15;            // channel f4 index (4 ch)
    const int vb  = t >> 4;            // voxel 0..15
    const int gr  = lb * 16 + vb;      // 16 | NV: no batch straddle
    const int b   = gr / NV;
    const int n   = gr - b * NV;
    const int d   = n / 576;
    const int rem = n - d * 576;
    const int r   = rem / 24;
    const int w   = rem - r * 24;
    const int n64 = n * 64;

    const float4 q0 = *(const float4*)(qw + (size_t)gr * 64 + c4i * 4);
    const float* kb = kw + (size_t)b * NV * 64 + c4i * 4;
    const float* vp = vw + (size_t)b * NV * 64 + c4i * 4;

    float logit[27];
    unsigned mb = 0;
    #pragma unroll
    for (int i3 = 0; i3 < 3; ++i3)
    #pragma unroll
    for (int j3 = 0; j3 < 3; ++j3)
    #pragma unroll
    for (int l3 = 0; l3 < 3; ++l3) {
        const int jj  = (i3 * 3 + j3) * 3 + l3;
        const int dd  = d + i3 - 1;
        const int rr  = r + j3 - 1;
        const int ww  = w + l3 - 1;
        const bool ok = ((unsigned)dd < 24u) & ((unsigned)rr < 24u) & ((unsigned)ww < 24u);
        const int OFF = ((i3 - 1) * 576 + (j3 - 1) * 24 + (l3 - 1)) * 64;
        const int nj  = n64 + (ok ? OFF : 0);
        const float4 kf = *(const float4*)(kb + (size_t)nj);
        const float a = q0.x * kf.x + q0.y * kf.y + q0.z * kf.z + q0.w * kf.w;
        logit[jj] = ok ? a : 0.f;
        mb |= (ok ? 1u : 0u) << jj;
    }

    #pragma unroll
    for (int j = 0; j < 27; ++j) logit[j] += __shfl_xor(logit[j], 1, 64);
    #pragma unroll
    for (int j = 0; j < 27; ++j) logit[j] += __shfl_xor(logit[j], 2, 64);

    float ssum = 0.f;
    #pragma unroll
    for (int j = 0; j < 27; ++j) {
        const float e = __expf(logit[j]);   // OOB: exp(0)=1 participates (ref)
        logit[j] = e;
        ssum += e;
    }
    const float inv = 1.f / ssum;

    float4 acc = make_float4(0.f, 0.f, 0.f, 0.f);
    #pragma unroll
    for (int i3 = 0; i3 < 3; ++i3)
    #pragma unroll
    for (int j3 = 0; j3 < 3; ++j3)
    #pragma unroll
    for (int l3 = 0; l3 < 3; ++l3) {
        const int jj  = (i3 * 3 + j3) * 3 + l3;
        const bool ok = (mb >> jj) & 1u;
        const int OFF = ((i3 - 1) * 576 + (j3 - 1) * 24 + (l3 - 1)) * 64;
        const int nj  = n64 + (ok ? OFF : 0);
        const float p = ok ? logit[jj] : 0.f;   // OOB contributes v = 0
        const float4 vf = *(const float4*)(vp + (size_t)nj);
        acc.x += p * vf.x; acc.y += p * vf.y;
        acc.z += p * vf.z; acc.w += p * vf.w;
    }
    acc.x *= inv; acc.y *= inv; acc.z *= inv; acc.w *= inv;

    sO4[vb * 17 + c4i] = acc;
    __syncthreads();

    // residual + channel-major store: 16 consecutive n per 16-lane group
    const int vv  = t & 15;
    const int cg  = t >> 4;            // channel group: c = cg + i*16
    const int bs  = (lb * 16) / NV;
    const int nb0 = lb * 16 - bs * NV;
    const float* sOf = (const float*)sO4;   // [vox][68 floats]
    const float* xb = x   + (size_t)bs * CCH * NV + nb0 + vv;
    float*       ob = out + (size_t)bs * CCH * NV + nb0 + vv;
    #pragma unroll
    for (int i = 0; i < 4; ++i) {
        const int c = cg + i * 16;
        ob[(size_t)c * NV] = xb[(size_t)c * NV] + sOf[vv * 68 + c];
    }
}

// ---------------------------------------------------------------------------
extern "C" void kernel_launch(void* const* d_in, const int* in_sizes, int n_in,
                              void* d_out, int out_size, void* d_ws, size_t ws_size,
                              hipStream_t stream) {
    const float* x  = (const float*)d_in[0];
    // d_in[1] = cemb, unused by the reference forward
    const float* Wq = (const float*)d_in[2];
    const float* bq = (const float*)d_in[3];
    const float* Wk = (const float*)d_in[4];
    const float* bk = (const float*)d_in[5];
    const float* Wv = (const float*)d_in[6];
    const float* bv = (const float*)d_in[7];
    float* out = (float*)d_out;

    float* ws = (float*)d_ws;
    const size_t RC = (size_t)NB * NV * CCH;   // 1,769,472 floats per tensor
    float* q = ws;
    float* k = ws + RC;
    float* v = ws + 2 * RC;

    qkv_kernel<<<1296, 256, 0, stream>>>(x, Wq, bq, Wk, bk, Wv, bv, q, k, v);
    attn_kernel<<<1728, 256, 0, stream>>>(x, q, k, v, out);
}